// Round 13
// baseline (128.468 us; speedup 1.0000x reference)
//
#include <hip/hip_runtime.h>

// B=4, CIN=COUT=64, H=W=128, 3x3 deformable conv, fp32 in/out.
// R13 = R12 with geometry change for real TLP:
//  - block = 4x8 px tile (2048 blocks x 256 thr = 4 waves: wq px-group x
//    half cin-group); halo +-2 (offset margin 4 sigma; exact cold path
//    covers the ~3e-5 tail) -> tile 9x13x64 bf16 = 16.8 KB, total LDS
//    19.2 KB -> 8 blocks/CU = 32 waves/CU (2x R12's real residency).
//  - loop bodies identical to R12 (64-VGPR, no-spill proven); gather row
//    stride becomes 13 pos (+936 shorts).
// Tells: LDS ~19.2 KB, VGPR 64, WRITE ~16.4 MB, occupancy >55%.

typedef __attribute__((ext_vector_type(8))) short short8x;
typedef __attribute__((ext_vector_type(4))) float float4x;
typedef unsigned short ushort;
typedef unsigned int uint;

__device__ __forceinline__ ushort f2bf(float f) {
    uint b = __float_as_uint(f);
    b += 0x7fffu + ((b >> 16) & 1u);
    return (ushort)(b >> 16);
}
__device__ __forceinline__ float bf2f(ushort u) {
    return __uint_as_float(((uint)u) << 16);
}

// ---------------------------------------------------------------------------
// Prologue: pack weights into MFMA B-fragment order (bf16). (R5 verbatim)
//  Bd [kk(18)][nt(4)][lane(64)][i(8)]: n = nt*16+(lane&15),
//     k = kk*32 + (lane>>4)*8 + i -> k2 = kk>>1, cin = (kk&1)*32+(lane>>4)*8+i
//  Bo [kk(18)][nt(2)][lane][i]: same, n>=18 zero-padded.
// ---------------------------------------------------------------------------
__global__ __launch_bounds__(256) void pack_weights(
    const float* __restrict__ w_def, const float* __restrict__ w_off,
    ushort* __restrict__ Bd, ushort* __restrict__ Bo) {
    int idx = blockIdx.x * 256 + threadIdx.x;
    if (idx < 36864) {
        int i = idx & 7;
        int lane = (idx >> 3) & 63;
        int nt = (idx >> 9) & 3;
        int kk = idx >> 11;
        int n = (nt << 4) + (lane & 15);
        int k2 = kk >> 1;
        int cin = ((kk & 1) << 5) + ((lane >> 4) << 3) + i;
        Bd[idx] = f2bf(w_def[(n * 64 + cin) * 9 + k2]);
    } else if (idx < 36864 + 18432) {
        int d = idx - 36864;
        int i = d & 7;
        int lane = (d >> 3) & 63;
        int nt = (d >> 9) & 1;
        int kk = d >> 10;
        int n = (nt << 4) + (lane & 15);
        int k2 = kk >> 1;
        int cin = ((kk & 1) << 5) + ((lane >> 4) << 3) + i;
        Bo[d] = (n < 18) ? f2bf(w_off[(n * 64 + cin) * 9 + k2]) : (ushort)0;
    }
}

// ---------------------------------------------------------------------------
// Fused kernel. Block = 4x8 pixel tile, 256 threads = 4 waves.
// wq = wv&1 owns pixels 16wq..16wq+15; half = wv>>1 owns cins 32half..+31
// (and n-group half in stage 1). Tile: 9 rows x 13 cols (halo +-2), LDS
// layout [pos][cin64+pad8] shorts; row stride = 13 pos = 936 shorts.
// ---------------------------------------------------------------------------
__global__ __launch_bounds__(256, 8) void dcn_fused(
    const float* __restrict__ x, const ushort* __restrict__ Bd,
    const ushort* __restrict__ Bo, const float* __restrict__ boff,
    const float* __restrict__ bdef, float* __restrict__ out) {

    int tid = threadIdx.x;
    int lane = tid & 63, wv = tid >> 6;
    int wq = wv & 1, half = wv >> 1;
    int blk = blockIdx.x;
    int b = blk >> 9, t = blk & 511;           // 512 tiles per batch image
    int h0 = (t >> 4) << 2, w0 = (t & 15) << 3;  // 32 tile-rows x 16 tile-cols

    // Manual shared layout (19152 B): tile 16848 B | offl 2304 B.
    // Epilogue reuses bytes 0..8320 as red[32][65] f32.
    __shared__ __align__(16) char smem[19152];
    ushort* tile = (ushort*)smem;              // [pos(117) stride 72][cin 64]
    float* offl = (float*)(smem + 16848);      // [px 32][ch 18]

    const float* xb = x + ((long)b << 20);

    // ---- stage halo: 234 units = (pos, cin-half), one unit per thread.
    if (tid < 234) {
        int pos = tid >> 1, ch = (tid & 1) << 5;
        int ty = pos / 13, tx = pos - ty * 13;
        int y = h0 - 2 + ty, xx = w0 - 2 + tx;
        bool valid = ((unsigned)y < 128u) & ((unsigned)xx < 128u);
        int yc = min(max(y, 0), 127), xc = min(max(xx, 0), 127);
        const float* gp = xb + ((long)ch << 14) + (yc << 7) + xc;
        uint4* trow = (uint4*)&tile[pos * 72 + ch];
#pragma unroll
        for (int c8 = 0; c8 < 4; ++c8) {
            const float* g8 = gp + (c8 << 17);
            float v[8];
#pragma unroll
            for (int j = 0; j < 8; ++j) v[j] = valid ? g8[j << 14] : 0.f;
            uint4 d;
            d.x = (uint)f2bf(v[0]) | ((uint)f2bf(v[1]) << 16);
            d.y = (uint)f2bf(v[2]) | ((uint)f2bf(v[3]) << 16);
            d.z = (uint)f2bf(v[4]) | ((uint)f2bf(v[5]) << 16);
            d.w = (uint)f2bf(v[6]) | ((uint)f2bf(v[7]) << 16);
            trow[c8] = d;
        }
    }
    __syncthreads();

    int l15 = lane & 15, lq = lane >> 4;
    int p1 = (wq << 4) + l15;          // this lane's A-row pixel (0..31)
    int plh = p1 >> 3, plw = p1 & 7;   // 4 rows x 8 cols

    // ---- stage 1: offset conv via MFMA, N-split by `half`. Full K=576.
    // Tile coords: sample (plh+kh-1, plw+kw-1) -> tile (plh+1+kh, plw+1+kw).
    float4x oacc = {0.f, 0.f, 0.f, 0.f};
#pragma unroll
    for (int k2 = 0; k2 < 9; ++k2) {
        int kh = k2 / 3, kw = k2 - kh * 3;
        int pos = (plh + 1 + kh) * 13 + (plw + 1 + kw);
        int abase = pos * 72 + (lq << 3);
#pragma unroll
        for (int hf = 0; hf < 2; ++hf) {
            int kk = k2 * 2 + hf;
            short8x a = *(const short8x*)&tile[abase + hf * 32];
            short8x bo = *(const short8x*)&Bo[(kk * 2 + half) * 512 + (lane << 3)];
            oacc = __builtin_amdgcn_mfma_f32_16x16x32_bf16(a, bo, oacc, 0, 0, 0);
        }
    }
    {   // scatter D (col n = 16*half + l15, row = lq*4+r) + bias -> offl
        int n = (half << 4) + l15;
        if (n < 18) {
            float bo = boff[n];
#pragma unroll
            for (int r = 0; r < 4; ++r) {
                int p = (wq << 4) + (lq << 2) + r;
                offl[p * 18 + n] = oacc[r] + bo;
            }
        }
    }
    __syncthreads();

    // ---- offsets to registers (constant-indexed only) + oob mask.
    // In-tile corner range: by in [0,7], bx in [0,11].
    float2 offr[9];
    uint oobmask = 0;
#pragma unroll
    for (int k2 = 0; k2 < 9; ++k2) {
        offr[k2] = *(const float2*)&offl[p1 * 18 + k2 * 2];
        const int kh = k2 / 3, kw = k2 - kh * 3;
        float sy = (float)(plh + 1 + kh) + offr[k2].x;
        float sx = (float)(plw + 1 + kw) + offr[k2].y;
        int by = (int)floorf(sy), bx = (int)floorf(sx);
        bool oob = ((unsigned)by > 7u) | ((unsigned)bx > 11u);
        oobmask |= oob ? (1u << k2) : 0u;
    }

    // ---- stage 2: 9 steps over this wave's cin-half (R12 loop body;
    // gather offsets: +72 = col+1, +936 = row+1)
    float4x acc[4];
#pragma unroll
    for (int nt = 0; nt < 4; ++nt) acc[nt] = (float4x){0.f, 0.f, 0.f, 0.f};

#pragma unroll
    for (int k2 = 0; k2 < 9; ++k2) {
        const int kh = k2 / 3, kw = k2 - kh * 3;
        float sy = (float)(plh + 1 + kh) + offr[k2].x;
        float sx = (float)(plw + 1 + kw) + offr[k2].y;
        float yf = floorf(sy), xf = floorf(sx);
        int by = (int)yf, bx = (int)xf;
        float wy1 = sy - yf, wx1 = sx - xf;
        float wy0 = 1.f - wy1, wx0 = 1.f - wx1;
        float w00 = wy0 * wx0, w01 = wy0 * wx1;
        float w10 = wy1 * wx0, w11 = wy1 * wx1;
        int byc = min(max(by, 0), 7), bxc = min(max(bx, 0), 11);
        int cb = (byc * 13 + bxc) * 72 + (lq << 3) + (half << 5);

        int kk = k2 * 2 + half;
        short8x c00 = *(const short8x*)&tile[cb];
        short8x c01 = *(const short8x*)&tile[cb + 72];
        short8x c10 = *(const short8x*)&tile[cb + 936];
        short8x c11 = *(const short8x*)&tile[cb + 1008];
        float s[8];
#pragma unroll
        for (int j = 0; j < 8; ++j) {
            s[j] = w00 * bf2f((ushort)c00[j]) + w01 * bf2f((ushort)c01[j])
                 + w10 * bf2f((ushort)c10[j]) + w11 * bf2f((ushort)c11[j]);
        }
        union { short8x v; ushort u[8]; } A;
#pragma unroll
        for (int j = 0; j < 8; ++j) A.u[j] = f2bf(s[j]);
#pragma unroll
        for (int nt = 0; nt < 4; ++nt) {
            short8x bw = *(const short8x*)&Bd[(kk * 4 + nt) * 512 + (lane << 3)];
            acc[nt] = __builtin_amdgcn_mfma_f32_16x16x32_bf16(A.v, bw, acc[nt], 0, 0, 0);
        }
    }

    // ---- cold exactness pass (own half): out-of-tile samples (|offset|>1,
    // ~3e-5 of samples — fires on ~3% of waves, exact). Recomputes from offl
    // (LDS); no dynamic indexing of register arrays (R8 lesson).
    if (__any(oobmask != 0)) {
#pragma unroll 1
        for (int k2 = 0; k2 < 9; ++k2) {
            if (!__any((oobmask >> k2) & 1)) continue;
            bool oob = (oobmask >> k2) & 1;
            const int kh = k2 / 3, kw = k2 - kh * 3;
            float2 od = *(const float2*)&offl[p1 * 18 + k2 * 2];
            float sy = (float)(plh + 1 + kh) + od.x;
            float sx = (float)(plw + 1 + kw) + od.y;
            float yf = floorf(sy), xf = floorf(sx);
            int by = (int)yf, bx = (int)xf;
            float wy1 = sy - yf, wx1 = sx - xf;
            float wy0 = 1.f - wy1, wx0 = 1.f - wx1;
            float w00 = wy0 * wx0, w01 = wy0 * wx1;
            float w10 = wy1 * wx0, w11 = wy1 * wx1;
            int byc = min(max(by, 0), 7), bxc = min(max(bx, 0), 11);
            int cb = (byc * 13 + bxc) * 72 + (lq << 3) + (half << 5);
            int y0g = by + h0 - 2, x0g = bx + w0 - 2;
            int y1g = y0g + 1, x1g = x0g + 1;
            float m00 = ((unsigned)y0g < 128u && (unsigned)x0g < 128u) ? w00 : 0.f;
            float m01 = ((unsigned)y0g < 128u && (unsigned)x1g < 128u) ? w01 : 0.f;
            float m10 = ((unsigned)y1g < 128u && (unsigned)x0g < 128u) ? w10 : 0.f;
            float m11 = ((unsigned)y1g < 128u && (unsigned)x1g < 128u) ? w11 : 0.f;
            int y0c = min(max(y0g, 0), 127), y1c = min(max(y1g, 0), 127);
            int x0c = min(max(x0g, 0), 127), x1c = min(max(x1g, 0), 127);
            int i00 = (y0c << 7) + x0c, i01 = (y0c << 7) + x1c;
            int i10 = (y1c << 7) + x0c, i11 = (y1c << 7) + x1c;
            int kk = k2 * 2 + half;
            int cin0 = (half << 5) + (lq << 3);
            short8x c00 = *(const short8x*)&tile[cb];
            short8x c01 = *(const short8x*)&tile[cb + 72];
            short8x c10 = *(const short8x*)&tile[cb + 936];
            short8x c11 = *(const short8x*)&tile[cb + 1008];
            float d[8];
#pragma unroll
            for (int j = 0; j < 8; ++j) {
                float sl = w00 * bf2f((ushort)c00[j]) + w01 * bf2f((ushort)c01[j])
                         + w10 * bf2f((ushort)c10[j]) + w11 * bf2f((ushort)c11[j]);
                const float* xp = xb + ((long)(cin0 + j) << 14);
                float sg = m00 * xp[i00] + m01 * xp[i01]
                         + m10 * xp[i10] + m11 * xp[i11];
                d[j] = oob ? (sg - sl) : 0.f;
            }
            union { short8x v; ushort u[8]; } A;
#pragma unroll
            for (int j = 0; j < 8; ++j) A.u[j] = f2bf(d[j]);
#pragma unroll
            for (int nt = 0; nt < 4; ++nt) {
                short8x bw = *(const short8x*)&Bd[(kk * 4 + nt) * 512 + (lane << 3)];
                acc[nt] = __builtin_amdgcn_mfma_f32_16x16x32_bf16(A.v, bw, acc[nt], 0, 0, 0);
            }
        }
    }

    // ---- reduce half pairs through LDS red[32][65] (pad-65: conflict-free;
    // doubles as the transpose layout for the store epilogue)
    __syncthreads();
    float* red = (float*)smem;   // 32*65*4 = 8320 B over tile
    if (half == 1) {
#pragma unroll
        for (int nt = 0; nt < 4; ++nt)
#pragma unroll
            for (int r = 0; r < 4; ++r) {
                int p = (wq << 4) + (lq << 2) + r;
                red[p * 65 + (nt << 4) + l15] = acc[nt][r];
            }
    }
    __syncthreads();
    if (half == 0) {
#pragma unroll
        for (int nt = 0; nt < 4; ++nt)
#pragma unroll
            for (int r = 0; r < 4; ++r) {
                int p = (wq << 4) + (lq << 2) + r;
                red[p * 65 + (nt << 4) + l15] += acc[nt][r];
            }
    }
    __syncthreads();

    // ---- store: thread = (cout n = tid>>2, row q = tid&3); 8 floats each
    {
        int n = tid >> 2, q = tid & 3;
        float bd = bdef[n];
        float* dst = out + (((long)(b * 64 + n)) << 14) + ((h0 + q) << 7) + w0;
        float v[8];
#pragma unroll
        for (int c = 0; c < 8; ++c) v[c] = red[(q * 8 + c) * 65 + n] + bd;
        float4x s0 = {v[0], v[1], v[2], v[3]};
        float4x s1 = {v[4], v[5], v[6], v[7]};
        *(float4x*)(dst) = s0;
        *(float4x*)(dst + 4) = s1;
    }
}

// ---------------------------------------------------------------------------
extern "C" void kernel_launch(void* const* d_in, const int* in_sizes, int n_in,
                              void* d_out, int out_size, void* d_ws, size_t ws_size,
                              hipStream_t stream) {
    const float* x     = (const float*)d_in[0];  // (4,64,128,128)
    const float* w_off = (const float*)d_in[1];  // (18,64,3,3)
    const float* b_off = (const float*)d_in[2];  // (18,)
    const float* w_def = (const float*)d_in[3];  // (64,64,3,3)
    const float* b_def = (const float*)d_in[4];  // (64,)
    float* out = (float*)d_out;                  // (4,64,128,128)

    ushort* Bd = (ushort*)d_ws;                  // 36864 bf16 = 73728 B
    ushort* Bo = Bd + 36864;                     // 18432 bf16 = 36864 B

    hipLaunchKernelGGL(pack_weights, dim3(216), dim3(256), 0, stream,
                       w_def, w_off, Bd, Bo);
    hipLaunchKernelGGL(dcn_fused, dim3(2048), dim3(256), 0, stream,
                       x, Bd, Bo, b_off, b_def, out);
}